// Round 3
// baseline (147.950 us; speedup 1.0000x reference)
//
#include <hip/hip_runtime.h>
#include <hip/hip_fp16.h>
#include <stdint.h>

// out[c,b,g] = sum_{s<8} prod_{l<3} x[b, I[c,g,s,l]]
//
// DIAGNOSTIC ROUND: identical algorithm/structure to R2, but the eval phase
// is executed REPS=16x (opaque zero offset defeats CSE/LICM; final rep is the
// real one, offset==0 -> output bit-identical). Purpose: surface our kernel
// in the top-5 rocprof rows (currently all harness poison-fills) to read its
// true duration (/16), occupancy, VGPR, SQ_LDS_BANK_CONFLICT, VALU/LDS split.
#define Cc 16
#define Gg 8192
#define Ss 8
#define Ll 3
#define Bb 32

#define BH 4                  // b-rows per slice (f16) -> 8 B per g column
#define NZ (Bb / BH)          // 8 slices
#define THREADS 512
#define ITERS 2
#define GCH (THREADS * ITERS) // 1024 g per block
#define NGC (Gg / GCH)        // 8 g-chunks
#define REPS 16               // eval-phase amplification (diagnostic)

// Evaluate one (c,g): 24 indices in q[6], 24 natural-layout ds_read_b64
// gathers (4 f16 b-values per index). zoff is 0 at runtime but opaque to the
// compiler, so repeated calls cannot be CSE'd/hoisted.
__device__ __forceinline__ void clause_eval(const uint2* __restrict__ xl2,
                                            const int4 q[6], float acc[4],
                                            int zoff) {
    #pragma unroll
    for (int h = 0; h < 2; ++h) {
        const int4 qa = q[3 * h + 0];
        const int4 qb = q[3 * h + 1];
        const int4 qc = q[3 * h + 2];
        int idx[12] = {qa.x, qa.y, qa.z, qa.w,
                       qb.x, qb.y, qb.z, qb.w,
                       qc.x, qc.y, qc.z, qc.w};
        uint2 r[12];
        #pragma unroll
        for (int k = 0; k < 12; ++k)             // independent ds_read_b64
            r[k] = xl2[(uint32_t)(idx[k] + zoff)];
        #pragma unroll
        for (int s = 0; s < 4; ++s) {
            const uint2 ra = r[3 * s + 0];
            const uint2 rb = r[3 * s + 1];
            const uint2 rd = r[3 * s + 2];
            __half2 p0 = __hmul2(__hmul2(*(const __half2*)&ra.x,
                                         *(const __half2*)&rb.x),
                                 *(const __half2*)&rd.x);   // b0,b1
            __half2 p1 = __hmul2(__hmul2(*(const __half2*)&ra.y,
                                         *(const __half2*)&rb.y),
                                 *(const __half2*)&rd.y);   // b2,b3
            float2 f0 = __half22float2(p0);
            float2 f1 = __half22float2(p1);
            acc[0] += f0.x;
            acc[1] += f0.y;
            acc[2] += f1.x;
            acc[3] += f1.y;
        }
    }
}

// Runs clause_eval REPS times; every rep re-opaques zoff (so loads are not
// loop-invariant) and keep-alives acc (so earlier reps are not DCE'd).
// zoff is 0 at runtime -> last rep's acc is the true result.
__device__ __forceinline__ void clause_eval_reps(const uint2* __restrict__ xl2,
                                                 const int4 q[6],
                                                 float accout[4]) {
    int zoff = 0;
    float a0 = 0.f, a1 = 0.f, a2 = 0.f, a3 = 0.f;
    #pragma unroll 1
    for (int rep = 0; rep < REPS; ++rep) {
        asm volatile("" : "+v"(zoff));           // fresh opaque value per rep
        float acc[4] = {0.f, 0.f, 0.f, 0.f};
        clause_eval(xl2, q, acc, zoff);
        asm volatile("" : "+v"(acc[0]), "+v"(acc[1]),
                          "+v"(acc[2]), "+v"(acc[3]));  // keep rep alive
        a0 = acc[0]; a1 = acc[1]; a2 = acc[2]; a3 = acc[3];
    }
    accout[0] = a0; accout[1] = a1; accout[2] = a2; accout[3] = a3;
}

__global__ __launch_bounds__(THREADS, 4) void clause_f16_diag(
        const float* __restrict__ x, const int* __restrict__ I,
        float* __restrict__ out) {
    __shared__ uint2 xl[Gg];                       // 64 KB
    const int tid = threadIdx.x;

    // 1024 blocks, 8 XCDs, 128 blocks/XCD; bijective since 1024 % 8 == 0.
    const int lb = (blockIdx.x & 7) * (1024 / 8) + (blockIdx.x >> 3);
    const int zh = lb & (NZ - 1);                  // slice
    const int gc = (lb >> 3) & (NGC - 1);          // g-chunk
    const int c  = lb >> 6;
    const int gbase = gc * GCH;

    // Prefetch both iterations' indices early (HBM latency hides under stage).
    const int g0 = gbase + tid;
    const int g1 = gbase + THREADS + tid;
    const int4* ip0 = (const int4*)(I + ((size_t)c * Gg + g0) * (Ss * Ll));
    const int4* ip1 = (const int4*)(I + ((size_t)c * Gg + g1) * (Ss * Ll));
    int4 q0[6], q1[6];
    #pragma unroll
    for (int k = 0; k < 6; ++k) q0[k] = ip0[k];
    #pragma unroll
    for (int k = 0; k < 6; ++k) q1[k] = ip1[k];

    // Stage slice zh (b-rows 4zh..4zh+3): 2 consecutive g columns per thread
    // per iteration -> coalesced float2 loads, conflict-free ds_write_b128.
    {
        const float* xs = x + (size_t)(BH * zh) * Gg;
        #pragma unroll 4
        for (int k = 0; k < Gg / (2 * THREADS); ++k) {   // 8 iterations
            const int g = 2 * (tid + k * THREADS);
            float2 v0 = *(const float2*)&xs[g];              // row b0
            float2 v1 = *(const float2*)&xs[Gg + g];         // row b1
            float2 v2 = *(const float2*)&xs[2 * (size_t)Gg + g];
            float2 v3 = *(const float2*)&xs[3 * (size_t)Gg + g];
            __half2 a01 = __floats2half2_rn(v0.x, v1.x);     // column g
            __half2 a23 = __floats2half2_rn(v2.x, v3.x);
            __half2 b01 = __floats2half2_rn(v0.y, v1.y);     // column g+1
            __half2 b23 = __floats2half2_rn(v2.y, v3.y);
            uint4 w = make_uint4(*(const uint32_t*)&a01, *(const uint32_t*)&a23,
                                 *(const uint32_t*)&b01, *(const uint32_t*)&b23);
            *(uint4*)&xl[g] = w;
        }
    }

    __syncthreads();                               // the ONE barrier

    float* opb = out + ((size_t)(c * Bb + BH * zh)) * Gg;

    {
        float acc[4];
        clause_eval_reps(xl, q0, acc);
        #pragma unroll
        for (int j = 0; j < 4; ++j)                // lane-consecutive g -> coalesced
            opb[(size_t)j * Gg + g0] = acc[j];
    }
    {
        float acc[4];
        clause_eval_reps(xl, q1, acc);
        #pragma unroll
        for (int j = 0; j < 4; ++j)
            opb[(size_t)j * Gg + g1] = acc[j];
    }
}

extern "C" void kernel_launch(void* const* d_in, const int* in_sizes, int n_in,
                              void* d_out, int out_size, void* d_ws, size_t ws_size,
                              hipStream_t stream) {
    const float* x = (const float*)d_in[0];
    const int* I = (const int*)d_in[1];
    float* out = (float*)d_out;
    (void)d_ws; (void)ws_size;                     // no workspace needed

    const int grid = Cc * NGC * NZ;                // 1024 blocks
    clause_f16_diag<<<grid, THREADS, 0, stream>>>(x, I, out);
}

// Round 4
// 80.548 us; speedup vs baseline: 1.8368x; 1.8368x over previous
//
#include <hip/hip_runtime.h>
#include <hip/hip_fp16.h>
#include <stdint.h>

// out[c,b,g] = sum_{s<8} prod_{l<3} x[b, I[c,g,s,l]]
//
// R4: stage-amortized single-round structure.
// R3 diagnostic: eval = 4.5 us, prologue (stage+convert+ramp) = 22.6 us of a
// 27 us kernel. The LDS image depends ONLY on zh (8 images), so stage it in
// 512 blocks (one round, 2/CU co-resident) and eval 4 clauses/thread.
#define Cc 16
#define Gg 8192
#define Ss 8
#define Ll 3
#define Bb 32

#define BH 4                  // b-rows per slice (f16) -> 8 B per g column
#define NZ (Bb / BH)          // 8 slices
#define THREADS 512

// Evaluate one (c,g): 24 indices in q[6], 24 natural-layout ds_read_b64
// gathers (4 f16 b-values per index). Two 12-index half-batches cap live
// gather registers at 24. All array indexing static after unroll.
__device__ __forceinline__ void clause_eval(const uint2* __restrict__ xl2,
                                            const int4 q[6], float acc[4]) {
    #pragma unroll
    for (int h = 0; h < 2; ++h) {
        const int4 qa = q[3 * h + 0];
        const int4 qb = q[3 * h + 1];
        const int4 qc = q[3 * h + 2];
        int idx[12] = {qa.x, qa.y, qa.z, qa.w,
                       qb.x, qb.y, qb.z, qb.w,
                       qc.x, qc.y, qc.z, qc.w};
        uint2 r[12];
        #pragma unroll
        for (int k = 0; k < 12; ++k)             // independent ds_read_b64
            r[k] = xl2[(uint32_t)idx[k]];
        #pragma unroll
        for (int s = 0; s < 4; ++s) {
            const uint2 ra = r[3 * s + 0];
            const uint2 rb = r[3 * s + 1];
            const uint2 rd = r[3 * s + 2];
            __half2 p0 = __hmul2(__hmul2(*(const __half2*)&ra.x,
                                         *(const __half2*)&rb.x),
                                 *(const __half2*)&rd.x);   // b0,b1
            __half2 p1 = __hmul2(__hmul2(*(const __half2*)&ra.y,
                                         *(const __half2*)&rb.y),
                                 *(const __half2*)&rd.y);   // b2,b3
            float2 f0 = __half22float2(p0);
            float2 f1 = __half22float2(p1);
            acc[0] += f0.x;
            acc[1] += f0.y;
            acc[2] += f1.x;
            acc[3] += f1.y;
        }
    }
}

#define EVAL_STORE(QBUF, CVAL, GVAL)                                          \
    {                                                                         \
        float acc[4] = {0.f, 0.f, 0.f, 0.f};                                  \
        clause_eval(xl, QBUF, acc);                                           \
        float* op = out + ((size_t)((CVAL) * Bb + BH * zh)) * Gg + (GVAL);    \
        __builtin_nontemporal_store(acc[0], &op[0]);                          \
        __builtin_nontemporal_store(acc[1], &op[(size_t)Gg]);                 \
        __builtin_nontemporal_store(acc[2], &op[2 * (size_t)Gg]);             \
        __builtin_nontemporal_store(acc[3], &op[3 * (size_t)Gg]);             \
    }

// 512 blocks x 512 threads: one round, 2 blocks/CU co-resident (64 KB LDS
// each), 16 waves/CU. Block = (zh, gc, cpair): stages slice zh ONCE, then
// evaluates c in {2cp, 2cp+1} x two 512-g subchunks = 4 evals/thread with
// double-buffered index prefetch (global latency hides under eval ds_reads).
// XCD swizzle: all 64 blocks of one cpair land on one XCD -> I fetched from
// HBM exactly once; x (1 MB) L2-resident per XCD.
__global__ __launch_bounds__(THREADS, 4) void clause_f16_1r(
        const float* __restrict__ x, const int* __restrict__ I,
        float* __restrict__ out) {
    __shared__ uint2 xl[Gg];                       // 64 KB
    const int tid = threadIdx.x;

    // 512 blocks, 8 XCDs, 64 blocks/XCD; bijective since 512 % 8 == 0.
    const int lb = (blockIdx.x & 7) * 64 + (blockIdx.x >> 3);
    const int zh = lb & (NZ - 1);                  // slice (twin-fastest)
    const int combo = lb >> 3;                     // [0,64)
    const int gc = combo & 7;                      // g-chunk of 1024
    const int cp = combo >> 3;                     // c-pair == XCD id
    const int gbase = gc * 1024;
    const int c0 = 2 * cp, c1 = 2 * cp + 1;
    const int g0 = gbase + tid;                    // subchunk 0
    const int g1 = gbase + THREADS + tid;          // subchunk 1

    // --- Stage issue: 16 float4 loads, ALL in flight (one vmcnt window).
    const float* xs = x + (size_t)(BH * zh) * Gg;
    float4 v[4][4];
    #pragma unroll
    for (int k = 0; k < 4; ++k) {
        const int g = 4 * tid + k * (4 * THREADS);
        #pragma unroll
        for (int r = 0; r < 4; ++r)
            v[k][r] = *(const float4*)&xs[(size_t)r * Gg + g];
    }

    // Issue iter-0 index loads (HBM) behind the stage loads.
    int4 qA[6], qB[6];
    {
        const int4* ip = (const int4*)(I + ((size_t)c0 * Gg + g0) * (Ss * Ll));
        #pragma unroll
        for (int k = 0; k < 6; ++k) qA[k] = ip[k];
    }

    // --- Convert + LDS write: per k, 4 g-columns -> 2x ds_write_b128
    // (contiguous 32 B/lane: full-bandwidth LDS burst).
    #pragma unroll
    for (int k = 0; k < 4; ++k) {
        const int g = 4 * tid + k * (4 * THREADS);
        const float4 r0 = v[k][0], r1 = v[k][1], r2 = v[k][2], r3 = v[k][3];
        __half2 l0 = __floats2half2_rn(r0.x, r1.x);
        __half2 h0 = __floats2half2_rn(r2.x, r3.x);
        __half2 l1 = __floats2half2_rn(r0.y, r1.y);
        __half2 h1 = __floats2half2_rn(r2.y, r3.y);
        __half2 l2 = __floats2half2_rn(r0.z, r1.z);
        __half2 h2v = __floats2half2_rn(r2.z, r3.z);
        __half2 l3 = __floats2half2_rn(r0.w, r1.w);
        __half2 h3 = __floats2half2_rn(r2.w, r3.w);
        uint4 w0 = make_uint4(*(const uint32_t*)&l0, *(const uint32_t*)&h0,
                              *(const uint32_t*)&l1, *(const uint32_t*)&h1);
        uint4 w1 = make_uint4(*(const uint32_t*)&l2, *(const uint32_t*)&h2v,
                              *(const uint32_t*)&l3, *(const uint32_t*)&h3);
        *(uint4*)&xl[g] = w0;
        *(uint4*)&xl[g + 2] = w1;
    }

    __syncthreads();                               // the ONE barrier

    // --- 4 eval iterations, double-buffered index prefetch, hand-unrolled
    // (static indexing everywhere; next iter's 6 int4 loads issue BEFORE the
    // current eval so HBM latency hides under 24 ds_read_b64 + VALU).
    {   // iter 0: (c0, g0); prefetch iter 1
        const int4* ip = (const int4*)(I + ((size_t)c0 * Gg + g1) * (Ss * Ll));
        #pragma unroll
        for (int k = 0; k < 6; ++k) qB[k] = ip[k];
        EVAL_STORE(qA, c0, g0)
    }
    {   // iter 1: (c0, g1); prefetch iter 2
        const int4* ip = (const int4*)(I + ((size_t)c1 * Gg + g0) * (Ss * Ll));
        #pragma unroll
        for (int k = 0; k < 6; ++k) qA[k] = ip[k];
        EVAL_STORE(qB, c0, g1)
    }
    {   // iter 2: (c1, g0); prefetch iter 3
        const int4* ip = (const int4*)(I + ((size_t)c1 * Gg + g1) * (Ss * Ll));
        #pragma unroll
        for (int k = 0; k < 6; ++k) qB[k] = ip[k];
        EVAL_STORE(qA, c1, g0)
    }
    {   // iter 3: (c1, g1)
        EVAL_STORE(qB, c1, g1)
    }
}

extern "C" void kernel_launch(void* const* d_in, const int* in_sizes, int n_in,
                              void* d_out, int out_size, void* d_ws, size_t ws_size,
                              hipStream_t stream) {
    const float* x = (const float*)d_in[0];
    const int* I = (const int*)d_in[1];
    float* out = (float*)d_out;
    (void)d_ws; (void)ws_size;                     // no workspace needed

    const int grid = 512;                          // 8 zh x 8 gc x 8 cpair
    clause_f16_1r<<<grid, THREADS, 0, stream>>>(x, I, out);
}

// Round 5
// 78.908 us; speedup vs baseline: 1.8750x; 1.0208x over previous
//
#include <hip/hip_runtime.h>
#include <hip/hip_fp16.h>
#include <stdint.h>

// out[c,b,g] = sum_{s<8} prod_{l<3} x[b, I[c,g,s,l]]
//
// R5: cold-phase split. Theory: the invariant ~22 us (across 3 null schedule
// changes) is the HBM-cold fetch of x+I after the 268 MB re-poison fill
// flushes L2+L3 each iteration. Prepass P streams the cold bytes at max MLP
// and compacts them (I int32->u16, x f32->f16 image); main kernel M consumes
// everything L3-warm with all indices prefetched upfront.
#define Cc 16
#define Gg 8192
#define Ss 8
#define Ll 3
#define Bb 32

#define BH 4                   // b-rows per slice (f16) -> 8 B per g column
#define NZ (Bb / BH)           // 8 slices
#define MTHREADS 512

// d_ws layout: [0, 512KB) f16 image xh[NZ][Gg][BH]; [512KB, +6.29MB) u16 I.
#define XH_BYTES  ((size_t)NZ * Gg * BH * 2)           // 524288
#define I16_OFF   XH_BYTES
#define I16_BYTES ((size_t)Cc * Gg * Ss * Ll * 2)      // 6291456

// ---- Kernel P: one streaming pass over the cold inputs.
//  blocks [0,64):   x-image build  xh[zh][g][0..3] = f16(x[4zh+j][g])
//  blocks [64,448): I pack int32 -> u16 (order-preserving), wave-contiguous
#define PB_X 64
#define PB_I 384
__global__ __launch_bounds__(256) void prepass(const float* __restrict__ x,
                                               const uint4* __restrict__ I4,
                                               uint4* __restrict__ ws4) {
    const int bid = blockIdx.x;
    if (bid < PB_X) {
        const int tt = bid * 256 + threadIdx.x;        // [0, 16384)
        const int zh = tt >> 11;                       // slice
        const int gg = (tt & 2047) << 2;               // 4 consecutive g
        const float* xr = x + (size_t)(4 * zh) * Gg + gg;
        float4 f0 = *(const float4*)&xr[0];
        float4 f1 = *(const float4*)&xr[Gg];
        float4 f2 = *(const float4*)&xr[2 * (size_t)Gg];
        float4 f3 = *(const float4*)&xr[3 * (size_t)Gg];
        __half2 lo0 = __floats2half2_rn(f0.x, f1.x), hi0 = __floats2half2_rn(f2.x, f3.x);
        __half2 lo1 = __floats2half2_rn(f0.y, f1.y), hi1 = __floats2half2_rn(f2.y, f3.y);
        __half2 lo2 = __floats2half2_rn(f0.z, f1.z), hi2 = __floats2half2_rn(f2.z, f3.z);
        __half2 lo3 = __floats2half2_rn(f0.w, f1.w), hi3 = __floats2half2_rn(f2.w, f3.w);
        uint4 w0 = make_uint4(*(uint32_t*)&lo0, *(uint32_t*)&hi0,
                              *(uint32_t*)&lo1, *(uint32_t*)&hi1);
        uint4 w1 = make_uint4(*(uint32_t*)&lo2, *(uint32_t*)&hi2,
                              *(uint32_t*)&lo3, *(uint32_t*)&hi3);
        uint4* dst = ws4 + ((size_t)zh << 12) + ((size_t)(tt & 2047) << 1);
        dst[0] = w0;                                   // 32 B/thread, coalesced
        dst[1] = w1;
    } else {
        // 98304 threads x 8 uint4 = all 786432 uint4 of I, wave-contiguous.
        const int t = (bid - PB_X) * 256 + threadIdx.x;
        uint2* ow = (uint2*)((char*)ws4 + I16_OFF);
        #pragma unroll
        for (int i = 0; i < 8; ++i) {
            const int e = t + i * (PB_I * 256);
            uint4 v = I4[e];
            uint2 o;
            o.x = (v.x & 0xffffu) | (v.y << 16);       // order-preserving pack
            o.y = (v.z & 0xffffu) | (v.w << 16);
            ow[e] = o;
        }
    }
}

// Evaluate one (c,g): 24 u16 indices in 3 uint4 regs; 24 natural-layout
// ds_read_b64 gathers. Two 12-gather half-batches cap live registers.
__device__ __forceinline__ void clause_eval16(const uint2* __restrict__ xl2,
                                              const uint4 q[3], float acc[4]) {
    const uint32_t u[12] = {q[0].x, q[0].y, q[0].z, q[0].w,
                            q[1].x, q[1].y, q[1].z, q[1].w,
                            q[2].x, q[2].y, q[2].z, q[2].w};
    #pragma unroll
    for (int h = 0; h < 2; ++h) {
        uint2 r[12];
        #pragma unroll
        for (int m = 0; m < 6; ++m) {
            const uint32_t w = u[6 * h + m];
            r[2 * m]     = xl2[w & 0xffffu];           // independent ds_read_b64
            r[2 * m + 1] = xl2[w >> 16];
        }
        #pragma unroll
        for (int s = 0; s < 4; ++s) {
            const uint2 ra = r[3 * s + 0];
            const uint2 rb = r[3 * s + 1];
            const uint2 rd = r[3 * s + 2];
            __half2 p0 = __hmul2(__hmul2(*(const __half2*)&ra.x,
                                         *(const __half2*)&rb.x),
                                 *(const __half2*)&rd.x);   // b0,b1
            __half2 p1 = __hmul2(__hmul2(*(const __half2*)&ra.y,
                                         *(const __half2*)&rb.y),
                                 *(const __half2*)&rd.y);   // b2,b3
            float2 f0 = __half22float2(p0);
            float2 f1 = __half22float2(p1);
            acc[0] += f0.x;
            acc[1] += f0.y;
            acc[2] += f1.x;
            acc[3] += f1.y;
        }
    }
}

#define QLOAD(QB, CV, GV)                                                     \
    {                                                                         \
        const uint4* p =                                                      \
            (const uint4*)(i16 + ((size_t)(CV) * Gg + (GV)) * (Ss * Ll));     \
        QB[0] = p[0]; QB[1] = p[1]; QB[2] = p[2];                             \
    }

#define EVAL_STORE(QB, CV, GV)                                                \
    {                                                                         \
        float acc[4] = {0.f, 0.f, 0.f, 0.f};                                  \
        clause_eval16(xl2, QB, acc);                                          \
        float* op = out + ((size_t)((CV) * Bb + BH * zh)) * Gg + (GV);        \
        __builtin_nontemporal_store(acc[0], &op[0]);                          \
        __builtin_nontemporal_store(acc[1], &op[(size_t)Gg]);                 \
        __builtin_nontemporal_store(acc[2], &op[2 * (size_t)Gg]);             \
        __builtin_nontemporal_store(acc[3], &op[3 * (size_t)Gg]);             \
    }

// ---- Kernel M: everything L3-warm. 512 blocks x 512 threads, 2 blocks/CU,
// one round. Stage = pure 128 B/thread copy (image pre-converted by P).
// All 4 iterations' indices prefetched upfront (u16-packed: 48 VGPRs total)
// -> the four evals run back-to-back with zero global dependency.
__global__ __launch_bounds__(MTHREADS, 4) void clause_m(
        const uint4* __restrict__ xh4, const ushort* __restrict__ i16,
        float* __restrict__ out) {
    __shared__ uint4 xl4[Gg / 2];                      // 64 KB
    const int tid = threadIdx.x;

    // XCD-bijective swizzle (512 % 8 == 0): one c-pair per XCD -> I region
    // L2-local; zh twin-fastest within the XCD.
    const int lb = (blockIdx.x & 7) * 64 + (blockIdx.x >> 3);
    const int zh = lb & (NZ - 1);
    const int combo = lb >> 3;
    const int gc = combo & 7;
    const int cp = combo >> 3;
    const int gbase = gc * 1024;
    const int c0 = 2 * cp, c1 = 2 * cp + 1;
    const int g0 = gbase + tid;
    const int g1 = gbase + MTHREADS + tid;

    // Stage loads: 8 x uint4 = the block's 64 KB slice (pure copy).
    const uint4* src = xh4 + ((size_t)zh << 12);
    uint4 st[8];
    #pragma unroll
    for (int i = 0; i < 8; ++i) st[i] = src[tid + i * MTHREADS];

    // All-q prefetch (12 x uint4, L3-warm) behind the stage loads.
    uint4 qA[3], qB[3], qC[3], qD[3];
    QLOAD(qA, c0, g0)
    QLOAD(qB, c0, g1)
    QLOAD(qC, c1, g0)
    QLOAD(qD, c1, g1)

    #pragma unroll
    for (int i = 0; i < 8; ++i) xl4[tid + i * MTHREADS] = st[i];

    __syncthreads();                                   // the ONE barrier

    const uint2* xl2 = (const uint2*)xl4;
    EVAL_STORE(qA, c0, g0)
    EVAL_STORE(qB, c0, g1)
    EVAL_STORE(qC, c1, g0)
    EVAL_STORE(qD, c1, g1)
}

// ---- Fallback (ws too small): direct global gather; slow but correct.
__global__ __launch_bounds__(256) void clause_kernel_direct(const float* __restrict__ x,
                                                            const int* __restrict__ I,
                                                            float* __restrict__ out) {
    const int tid = threadIdx.x;
    const int b = tid & 31;
    const int j = tid >> 5;
    const int g = blockIdx.x * 8 + j;
    const int c = blockIdx.y;

    const int* Icg = I + (size_t)(c * Gg + g) * (Ss * Ll);
    float sum = 0.f;
    #pragma unroll
    for (int s = 0; s < Ss; ++s) {
        float p0 = x[(size_t)b * Gg + Icg[3 * s + 0]];
        float p1 = x[(size_t)b * Gg + Icg[3 * s + 1]];
        float p2 = x[(size_t)b * Gg + Icg[3 * s + 2]];
        sum += p0 * p1 * p2;
    }
    out[(size_t)(c * Bb + b) * Gg + g] = sum;
}

extern "C" void kernel_launch(void* const* d_in, const int* in_sizes, int n_in,
                              void* d_out, int out_size, void* d_ws, size_t ws_size,
                              hipStream_t stream) {
    const float* x = (const float*)d_in[0];
    const int* I = (const int*)d_in[1];
    float* out = (float*)d_out;

    const size_t need = I16_OFF + I16_BYTES;           // ~6.82 MB
    if (ws_size >= need) {
        prepass<<<PB_X + PB_I, 256, 0, stream>>>(x, (const uint4*)I,
                                                 (uint4*)d_ws);
        clause_m<<<512, MTHREADS, 0, stream>>>(
            (const uint4*)d_ws, (const ushort*)((char*)d_ws + I16_OFF), out);
    } else {
        clause_kernel_direct<<<dim3(Gg / 8, Cc), 256, 0, stream>>>(x, I, out);
    }
}